// Round 1
// baseline (709.940 us; speedup 1.0000x reference)
//
#include <hip/hip_runtime.h>

typedef __bf16 bf16;
typedef __bf16 bf16x8 __attribute__((ext_vector_type(8)));
typedef __bf16 bf16x4 __attribute__((ext_vector_type(4)));
typedef float  f32x4  __attribute__((ext_vector_type(4)));

// Problem constants
#define BATCH   16
#define CDIM    512      // DIM
#define NSPAT   4096     // H*W
#define QKV_M   1536     // 3*INNER
#define INNER   512

// ---------------------------------------------------------------------------
// f32 -> bf16 cast (vectorized by 4)
// ---------------------------------------------------------------------------
__global__ __launch_bounds__(256) void cast_f32_bf16_kernel(
    const float* __restrict__ in, bf16* __restrict__ out, int n4) {
  int i = blockIdx.x * 256 + threadIdx.x;
  if (i >= n4) return;
  float4 v = ((const float4*)in)[i];
  bf16x4 o = { (bf16)v.x, (bf16)v.y, (bf16)v.z, (bf16)v.w };
  *(bf16x4*)(out + (size_t)i * 4) = o;
}

// ---------------------------------------------------------------------------
// Batched GEMM: C[b] = A (MxK, shared weights) * X[b] (KxN), bf16 in, fp32 acc
// Tile: 128x128, BK=32, 256 threads = 4 waves (2x2), each wave 4x4 16x16 tiles
// OUTMODE 0: bf16 output, no bias. OUTMODE 1: f32 output + bias.
// ---------------------------------------------------------------------------
template <int OUTMODE>
__global__ __launch_bounds__(256) void gemm_bf16_kernel(
    const bf16* __restrict__ A, const bf16* __restrict__ X,
    void* __restrict__ Cout, const float* __restrict__ bias,
    int M, int N, int K) {
  // As: [m][k] (k-contiguous).  Bs: [n][k] (k-contiguous, transposed at stage).
  // row stride 40 shorts = 80 B keeps 16B alignment for ds_read_b128.
  __shared__ __attribute__((aligned(16))) bf16 As[128][40];
  __shared__ __attribute__((aligned(16))) bf16 Bs[128][40];

  int b  = blockIdx.z;
  int m0 = blockIdx.y * 128, n0 = blockIdx.x * 128;
  const bf16* Xb = X + (size_t)b * K * N;

  int tid  = threadIdx.x;
  int lane = tid & 63, wid = tid >> 6;
  int wm = wid >> 1, wn = wid & 1;
  int lm = lane & 15, kqd = lane >> 4;

  f32x4 acc[4][4] = {};

  for (int k0 = 0; k0 < K; k0 += 32) {
    // Stage A: 128 rows x 32 k, vector 16B loads and writes.
#pragma unroll
    for (int i = 0; i < 2; ++i) {
      int v = tid + i * 256;          // 512 vec8
      int m = v >> 2, kv = (v & 3) * 8;
      *(bf16x8*)(&As[m][kv]) = *(const bf16x8*)(A + (size_t)(m0 + m) * K + k0 + kv);
    }
    // Stage B transposed: lane-major over k rows so the scalar LDS writes are
    // conflict-free (consecutive lanes -> consecutive k columns).
#pragma unroll
    for (int i = 0; i < 2; ++i) {
      int v = tid + i * 256;          // 512 vec8
      int kk = v & 31, nv = (v >> 5) * 8;
      bf16x8 d = *(const bf16x8*)(Xb + (size_t)(k0 + kk) * N + n0 + nv);
#pragma unroll
      for (int j = 0; j < 8; ++j) Bs[nv + j][kk] = d[j];
    }
    __syncthreads();

    bf16x8 af[4], bfr[4];
#pragma unroll
    for (int im = 0; im < 4; ++im)
      af[im] = *(const bf16x8*)(&As[wm * 64 + im * 16 + lm][kqd * 8]);
#pragma unroll
    for (int in = 0; in < 4; ++in)
      bfr[in] = *(const bf16x8*)(&Bs[wn * 64 + in * 16 + lm][kqd * 8]);
#pragma unroll
    for (int im = 0; im < 4; ++im)
#pragma unroll
      for (int in = 0; in < 4; ++in)
        acc[im][in] = __builtin_amdgcn_mfma_f32_16x16x32_bf16(af[im], bfr[in], acc[im][in], 0, 0, 0);
    __syncthreads();
  }

  // Epilogue. C/D layout: col = lane&15, row = (lane>>4)*4 + r  [m89-verified]
#pragma unroll
  for (int im = 0; im < 4; ++im) {
#pragma unroll
    for (int in = 0; in < 4; ++in) {
      int row = m0 + wm * 64 + im * 16 + kqd * 4;
      int col = n0 + wn * 64 + in * 16 + lm;
      if (OUTMODE == 0) {
        bf16* C = (bf16*)Cout + (size_t)b * M * N;
#pragma unroll
        for (int r = 0; r < 4; ++r)
          C[(size_t)(row + r) * N + col] = (bf16)acc[im][in][r];
      } else {
        float* C = (float*)Cout + (size_t)b * M * N;
#pragma unroll
        for (int r = 0; r < 4; ++r)
          C[(size_t)(row + r) * N + col] = acc[im][in][r] + bias[row + r];
      }
    }
  }
}

// ---------------------------------------------------------------------------
// Fused channel attention per (b,h): scores = q k^T / 8 (64x64, K=4096),
// softmax rows, out = attn * v (64x4096, K=64). One block (4 waves) per (b,h).
// ---------------------------------------------------------------------------
__global__ __launch_bounds__(256) void attn_kernel(
    const bf16* __restrict__ qkv,   // (B, 1536, 4096)
    bf16* __restrict__ attnout) {   // (B, 512, 4096)
  __shared__ float sc[64][66];
  __shared__ __attribute__((aligned(16))) bf16 attn_s[64][72];
  __shared__ __attribute__((aligned(16))) bf16 Vs[128][72];   // [n][e]

  int bh = blockIdx.x, b = bh >> 3, h = bh & 7;
  const bf16* q    = qkv + ((size_t)b * QKV_M + h * 64) * NSPAT;
  const bf16* kmat = q + (size_t)INNER * NSPAT;
  const bf16* vmat = q + (size_t)(2 * INNER) * NSPAT;

  int tid = threadIdx.x, lane = tid & 63, wid = tid >> 6;
  int lm = lane & 15, kqd = lane >> 4;
  int d0 = wid * 16;   // each wave owns a 16-row d-block

  // Phase 1: scores. Both MFMA operands are n-contiguous -> direct 16B global loads.
  f32x4 acc[4] = {};
  for (int n0 = 0; n0 < NSPAT; n0 += 32) {
    bf16x8 a = *(const bf16x8*)(q + (size_t)(d0 + lm) * NSPAT + n0 + kqd * 8);
#pragma unroll
    for (int eb = 0; eb < 4; ++eb) {
      bf16x8 bb = *(const bf16x8*)(kmat + (size_t)(eb * 16 + lm) * NSPAT + n0 + kqd * 8);
      acc[eb] = __builtin_amdgcn_mfma_f32_16x16x32_bf16(a, bb, acc[eb], 0, 0, 0);
    }
  }
#pragma unroll
  for (int eb = 0; eb < 4; ++eb)
#pragma unroll
    for (int r = 0; r < 4; ++r)
      sc[d0 + kqd * 4 + r][eb * 16 + lm] = acc[eb][r] * 0.125f;
  __syncthreads();

  // Phase 2: softmax (one thread per row; 64 rows)
  if (tid < 64) {
    float mx = -1e30f;
    for (int e = 0; e < 64; ++e) mx = fmaxf(mx, sc[tid][e]);
    float s = 0.f;
    for (int e = 0; e < 64; ++e) { float ex = expf(sc[tid][e] - mx); sc[tid][e] = ex; s += ex; }
    float inv = 1.0f / s;
    for (int e = 0; e < 64; ++e) attn_s[tid][e] = (bf16)(sc[tid][e] * inv);
  }
  __syncthreads();

  // Phase 3: PV. A-frags (attn rows) loaded once; V staged transposed per n-chunk.
  bf16x8 a0 = *(const bf16x8*)(&attn_s[d0 + lm][kqd * 8]);
  bf16x8 a1 = *(const bf16x8*)(&attn_s[d0 + lm][32 + kqd * 8]);
  bf16* outp = attnout + ((size_t)b * INNER + h * 64) * NSPAT;

  for (int nc = 0; nc < NSPAT; nc += 128) {
    __syncthreads();   // protect Vs reuse
#pragma unroll
    for (int i = 0; i < 4; ++i) {
      int v = i * 256 + tid;          // 1024 vec8: e = v&63 (lane-major => conflict-free writes)
      int e = v & 63, nn = (v >> 6) * 8;
      bf16x8 d = *(const bf16x8*)(vmat + (size_t)e * NSPAT + nc + nn);
#pragma unroll
      for (int j = 0; j < 8; ++j) Vs[nn + j][e] = d[j];
    }
    __syncthreads();
#pragma unroll
    for (int nt = 0; nt < 8; ++nt) {
      bf16x8 b0 = *(const bf16x8*)(&Vs[nt * 16 + lm][kqd * 8]);
      bf16x8 b1 = *(const bf16x8*)(&Vs[nt * 16 + lm][32 + kqd * 8]);
      f32x4 o = {};
      o = __builtin_amdgcn_mfma_f32_16x16x32_bf16(a0, b0, o, 0, 0, 0);
      o = __builtin_amdgcn_mfma_f32_16x16x32_bf16(a1, b1, o, 0, 0, 0);
#pragma unroll
      for (int r = 0; r < 4; ++r)
        outp[(size_t)(d0 + kqd * 4 + r) * NSPAT + nc + nt * 16 + lm] = (bf16)o[r];
    }
  }
}

// ---------------------------------------------------------------------------
// LayerNorm over (C,H,W) per batch: partial sums -> stats -> apply affine
// ---------------------------------------------------------------------------
__global__ __launch_bounds__(256) void ln_partial_kernel(
    const float* __restrict__ out, float2* __restrict__ part) {
  int b = blockIdx.y, ch = blockIdx.x;
  const float4* p = (const float4*)(out + (size_t)b * 2097152 + (size_t)ch * 65536);
  float s = 0.f, s2 = 0.f;
  for (int i = threadIdx.x; i < 16384; i += 256) {
    float4 v = p[i];
    s  += v.x + v.y + v.z + v.w;
    s2 += v.x * v.x + v.y * v.y + v.z * v.z + v.w * v.w;
  }
#pragma unroll
  for (int off = 32; off > 0; off >>= 1) {
    s  += __shfl_down(s, off, 64);
    s2 += __shfl_down(s2, off, 64);
  }
  __shared__ float ls[4], ls2[4];
  int lane = threadIdx.x & 63, wid = threadIdx.x >> 6;
  if (lane == 0) { ls[wid] = s; ls2[wid] = s2; }
  __syncthreads();
  if (threadIdx.x == 0)
    part[b * 32 + ch] = make_float2(ls[0] + ls[1] + ls[2] + ls[3],
                                    ls2[0] + ls2[1] + ls2[2] + ls2[3]);
}

__global__ void ln_stats_kernel(const float2* __restrict__ part, float2* __restrict__ stats) {
  int b = blockIdx.x;
  if (threadIdx.x == 0) {
    float s = 0.f, s2 = 0.f;
    for (int i = 0; i < 32; ++i) { float2 p = part[b * 32 + i]; s += p.x; s2 += p.y; }
    const float invn = 1.0f / 2097152.0f;
    float mean = s * invn;
    float var  = s2 * invn - mean * mean;
    stats[b] = make_float2(mean, rsqrtf(var + 1e-5f));
  }
}

__global__ __launch_bounds__(256) void ln_apply_kernel(
    float* __restrict__ out, const float2* __restrict__ stats,
    const float* __restrict__ gamma, const float* __restrict__ beta) {
  size_t i4 = (size_t)blockIdx.x * 256 + threadIdx.x;
  size_t e  = i4 * 4;
  int b = (int)(e >> 21);          // 512*4096 = 2^21
  int c = (int)((e >> 12) & 511);  // channel
  float2 st = stats[b];
  float g  = gamma[c] * st.y;
  float bb = beta[c] - st.x * g;
  float4* p = (float4*)out;
  float4 v = p[i4];
  v.x = v.x * g + bb; v.y = v.y * g + bb; v.z = v.z * g + bb; v.w = v.w * g + bb;
  p[i4] = v;
}

// ---------------------------------------------------------------------------
extern "C" void kernel_launch(void* const* d_in, const int* in_sizes, int n_in,
                              void* d_out, int out_size, void* d_ws, size_t ws_size,
                              hipStream_t stream) {
  const float* x      = (const float*)d_in[0];
  const float* w_qkv  = (const float*)d_in[1];
  const float* w_out  = (const float*)d_in[2];
  const float* b_out  = (const float*)d_in[3];
  const float* gamma  = (const float*)d_in[4];
  const float* beta   = (const float*)d_in[5];
  float* out = (float*)d_out;

  char* ws = (char*)d_ws;
  bf16*   xb    = (bf16*)(ws);                       //  64 MiB (16,512,4096)
  bf16*   wqkvb = (bf16*)(ws + 67108864);            // 1.5 MiB (1536,512)
  bf16*   woutb = (bf16*)(ws + 68681728);            // 0.5 MiB (512,512)
  bf16*   qkvb  = (bf16*)(ws + 69206016);            // 192 MiB (16,1536,4096)
  bf16*   attnb = (bf16*)(ws + 270532608);           //  64 MiB (16,512,4096)
  float2* part  = (float2*)(ws + 337641472);         // 16*32 partials
  float2* stats = (float2*)(ws + 337645568);         // 16 (mean, rstd)

  // casts
  cast_f32_bf16_kernel<<<32768, 256, 0, stream>>>(x, xb, 8388608);
  cast_f32_bf16_kernel<<<768,   256, 0, stream>>>(w_qkv, wqkvb, 196608);
  cast_f32_bf16_kernel<<<256,   256, 0, stream>>>(w_out, woutb, 65536);

  // QKV projection: (1536x512) x (512x4096) per batch
  gemm_bf16_kernel<0><<<dim3(32, 12, BATCH), 256, 0, stream>>>(
      wqkvb, xb, (void*)qkvb, nullptr, QKV_M, NSPAT, CDIM);

  // fused channel attention
  attn_kernel<<<BATCH * 8, 256, 0, stream>>>(qkvb, attnb);

  // output projection + bias -> d_out (fp32)
  gemm_bf16_kernel<1><<<dim3(32, 4, BATCH), 256, 0, stream>>>(
      woutb, attnb, (void*)out, b_out, INNER, NSPAT, CDIM);

  // per-batch layernorm + affine
  ln_partial_kernel<<<dim3(32, BATCH), 256, 0, stream>>>(out, part);
  ln_stats_kernel<<<BATCH, 64, 0, stream>>>(part, stats);
  ln_apply_kernel<<<32768, 256, 0, stream>>>(out, stats, gamma, beta);
}

// Round 2
// 573.980 us; speedup vs baseline: 1.2369x; 1.2369x over previous
//
#include <hip/hip_runtime.h>

typedef __bf16 bf16;
typedef __bf16 bf16x8 __attribute__((ext_vector_type(8)));
typedef __bf16 bf16x4 __attribute__((ext_vector_type(4)));
typedef float  f32x4  __attribute__((ext_vector_type(4)));

#define BATCH   16
#define CDIM    512
#define NSPAT   4096
#define QKV_M   1536
#define INNER   512

// async global->LDS, 16B per lane; LDS dest = wave-uniform base + lane*16
__device__ __forceinline__ void gld16(const bf16* g, const bf16* l) {
  __builtin_amdgcn_global_load_lds(
      (const __attribute__((address_space(1))) void*)g,
      (__attribute__((address_space(3))) void*)l, 16, 0, 0);
}

// ---------------------------------------------------------------------------
// f32 -> bf16 cast (weights)
// ---------------------------------------------------------------------------
__global__ __launch_bounds__(256) void cast_f32_bf16_kernel(
    const float* __restrict__ in, bf16* __restrict__ out, int n4) {
  int i = blockIdx.x * 256 + threadIdx.x;
  if (i >= n4) return;
  float4 v = ((const float4*)in)[i];
  bf16x4 o = { (bf16)v.x, (bf16)v.y, (bf16)v.z, (bf16)v.w };
  *(bf16x4*)(out + (size_t)i * 4) = o;
}

// ---------------------------------------------------------------------------
// x (B, C=512, N=4096) f32 -> xt (B, N, C) bf16   (64x64 LDS tile transpose)
// ---------------------------------------------------------------------------
__global__ __launch_bounds__(256) void transpose_cast_kernel(
    const float* __restrict__ x, bf16* __restrict__ xt) {
  __shared__ __attribute__((aligned(16))) bf16 T[64][72];
  int b = blockIdx.z, c0 = blockIdx.y * 64, n0 = blockIdx.x * 64;
  int t = threadIdx.x;
  const float* xp = x + ((size_t)b * CDIM + c0) * NSPAT + n0;
#pragma unroll
  for (int i = 0; i < 4; ++i) {
    int v = t + i * 256;
    int c = v >> 4, nq = (v & 15) * 4;
    float4 rd = *(const float4*)(xp + (size_t)c * NSPAT + nq);
    T[nq + 0][c] = (bf16)rd.x; T[nq + 1][c] = (bf16)rd.y;
    T[nq + 2][c] = (bf16)rd.z; T[nq + 3][c] = (bf16)rd.w;
  }
  __syncthreads();
  bf16* op = xt + ((size_t)b * NSPAT + n0) * CDIM + c0;
#pragma unroll
  for (int i = 0; i < 2; ++i) {
    int v = t + i * 256;
    int n = v >> 3, cc = (v & 7) * 8;
    *(bf16x8*)(op + (size_t)n * CDIM + cc) = *(const bf16x8*)&T[n][cc];
  }
}

// ---------------------------------------------------------------------------
// GEMM (m97 structure): C[b] = A(M,K) * Bt[b](N,K)^T, both k-contiguous.
// 128x128 tile, BK=32, global_load_lds staging, 4 waves x (4x4) 16x16x32 MFMA.
// OUTMODE 0: bf16 C via per-wave LDS-transposed b128 stores.
// OUTMODE 1: f32 C + bias + per-batch LN partial sums (atomicAdd).
// ---------------------------------------------------------------------------
template <int OUTMODE>
__global__ __launch_bounds__(256) void gemm_tn_kernel(
    const bf16* __restrict__ A, const bf16* __restrict__ Bt,
    void* __restrict__ Cout, const float* __restrict__ bias,
    float* __restrict__ part, int M, int N, int K) {
  __shared__ __attribute__((aligned(16))) bf16 smem[8192];  // As[4096] ++ Bs[4096]

  int b  = blockIdx.z;
  int m0 = blockIdx.y * 128, n0 = blockIdx.x * 128;
  const bf16* Ab = A + (size_t)m0 * K;
  const bf16* Bb = Bt + ((size_t)b * N + n0) * K;

  int tid = threadIdx.x, lane = tid & 63, wid = tid >> 6;
  int wm = wid >> 1, wn = wid & 1, lm = lane & 15, kqd = lane >> 4;
  int srow = lane >> 2, skb = lane & 3;

  f32x4 acc[4][4] = {};

  for (int k0 = 0; k0 < K; k0 += 32) {
#pragma unroll
    for (int i = 0; i < 2; ++i) {
      int gi = wid * 2 + i;
      gld16(Ab + (size_t)(gi * 16 + srow) * K + k0 + skb * 8, smem + gi * 512);
      gld16(Bb + (size_t)(gi * 16 + srow) * K + k0 + skb * 8, smem + 4096 + gi * 512);
    }
    __syncthreads();
    bf16x8 af[4], bfr[4];
#pragma unroll
    for (int im = 0; im < 4; ++im)
      af[im] = *(const bf16x8*)&smem[(wm * 64 + im * 16 + lm) * 32 + kqd * 8];
#pragma unroll
    for (int in = 0; in < 4; ++in)
      bfr[in] = *(const bf16x8*)&smem[4096 + (wn * 64 + in * 16 + lm) * 32 + kqd * 8];
#pragma unroll
    for (int im = 0; im < 4; ++im)
#pragma unroll
      for (int in = 0; in < 4; ++in)
        acc[im][in] = __builtin_amdgcn_mfma_f32_16x16x32_bf16(af[im], bfr[in], acc[im][in], 0, 0, 0);
    __syncthreads();
  }

  // C/D layout: col = lane&15, row = (lane>>4)*4 + r
  if (OUTMODE == 0) {
    bf16* C = (bf16*)Cout + (size_t)b * M * N;
    bf16* Ws = smem + wid * 2048;   // per-wave 32x64 staging (no barriers needed)
#pragma unroll
    for (int half = 0; half < 2; ++half) {
#pragma unroll
      for (int im2 = 0; im2 < 2; ++im2) {
        int im = half * 2 + im2;
#pragma unroll
        for (int in = 0; in < 4; ++in)
#pragma unroll
          for (int r = 0; r < 4; ++r)
            Ws[(im2 * 16 + kqd * 4 + r) * 64 + in * 16 + lm] = (bf16)acc[im][in][r];
      }
#pragma unroll
      for (int j = 0; j < 4; ++j) {
        int u = lane + j * 64;
        int row = u >> 3, cu = (u & 7) * 8;
        *(bf16x8*)(C + (size_t)(m0 + wm * 64 + half * 32 + row) * N + n0 + wn * 64 + cu) =
            *(const bf16x8*)&Ws[row * 64 + cu];
      }
    }
  } else {
    float* C = (float*)Cout + (size_t)b * M * N;
    float s = 0.f, s2 = 0.f;
#pragma unroll
    for (int im = 0; im < 4; ++im)
#pragma unroll
      for (int in = 0; in < 4; ++in) {
        int row = m0 + wm * 64 + im * 16 + kqd * 4;
        int col = n0 + wn * 64 + in * 16 + lm;
#pragma unroll
        for (int r = 0; r < 4; ++r) {
          float v = acc[im][in][r] + bias[row + r];
          C[(size_t)(row + r) * N + col] = v;
          s += v; s2 += v * v;
        }
      }
#pragma unroll
    for (int off = 32; off > 0; off >>= 1) {
      s  += __shfl_down(s, off, 64);
      s2 += __shfl_down(s2, off, 64);
    }
    __shared__ float red[8];
    if (lane == 0) { red[wid] = s; red[wid + 4] = s2; }
    __syncthreads();
    if (tid == 0) {
      atomicAdd(&part[b * 2],     red[0] + red[1] + red[2] + red[3]);
      atomicAdd(&part[b * 2 + 1], red[4] + red[5] + red[6] + red[7]);
    }
  }
}

// ---------------------------------------------------------------------------
// Attention scores, chunked: partial sc[bh][chunk][d][e] = sum_{n in chunk} q*k
// grid (8 chunks, 128 bh). glds-staged Q/K tiles, 4 waves x 16 d-rows.
// ---------------------------------------------------------------------------
__global__ __launch_bounds__(256) void attn_scores_kernel(
    const bf16* __restrict__ qkv, float* __restrict__ sc_part) {
  __shared__ __attribute__((aligned(16))) bf16 qs[4096];  // Qs[2048] ++ Ks[2048]
  int chunk = blockIdx.x, bh = blockIdx.y, b = bh >> 3, h = bh & 7;
  const bf16* q = qkv + ((size_t)b * QKV_M + h * 64) * NSPAT + chunk * 512;
  const bf16* k = q + (size_t)INNER * NSPAT;

  int tid = threadIdx.x, lane = tid & 63, wid = tid >> 6;
  int lm = lane & 15, kqd = lane >> 4, d0 = wid * 16;
  int srow = lane >> 2, skb = lane & 3;

  f32x4 acc[4] = {};
  for (int n0 = 0; n0 < 512; n0 += 32) {
    gld16(q + (size_t)(wid * 16 + srow) * NSPAT + n0 + skb * 8, qs + wid * 512);
    gld16(k + (size_t)(wid * 16 + srow) * NSPAT + n0 + skb * 8, qs + 2048 + wid * 512);
    __syncthreads();
    bf16x8 a = *(const bf16x8*)&qs[(d0 + lm) * 32 + kqd * 8];
#pragma unroll
    for (int eb = 0; eb < 4; ++eb) {
      bf16x8 bb = *(const bf16x8*)&qs[2048 + (eb * 16 + lm) * 32 + kqd * 8];
      acc[eb] = __builtin_amdgcn_mfma_f32_16x16x32_bf16(a, bb, acc[eb], 0, 0, 0);
    }
    __syncthreads();
  }
  float* outp = sc_part + ((size_t)bh * 8 + chunk) * 4096;
#pragma unroll
  for (int eb = 0; eb < 4; ++eb)
#pragma unroll
    for (int r = 0; r < 4; ++r)
      outp[(d0 + kqd * 4 + r) * 64 + eb * 16 + lm] = acc[eb][r];
}

// ---------------------------------------------------------------------------
// Softmax: sum 8 partial chunks, scale 1/8, softmax rows, bf16 attn weights
// ---------------------------------------------------------------------------
__global__ __launch_bounds__(256) void attn_softmax_kernel(
    const float* __restrict__ sc_part, bf16* __restrict__ attn_w) {
  __shared__ float ssum[64][65];
  int bh = blockIdx.x, t = threadIdx.x;
  const float* p = sc_part + (size_t)bh * 8 * 4096;
  float v[16];
#pragma unroll
  for (int j = 0; j < 16; ++j) v[j] = p[t + j * 256];
  for (int c = 1; c < 8; ++c)
#pragma unroll
    for (int j = 0; j < 16; ++j) v[j] += p[c * 4096 + t + j * 256];
#pragma unroll
  for (int j = 0; j < 16; ++j) {
    int q = t + j * 256;
    ssum[q >> 6][q & 63] = v[j];
  }
  __syncthreads();
  if (t < 64) {
    float mx = -1e30f;
    for (int e = 0; e < 64; ++e) mx = fmaxf(mx, ssum[t][e]);
    float s = 0.f;
    for (int e = 0; e < 64; ++e) {
      float ex = __expf((ssum[t][e] - mx) * 0.125f);
      ssum[t][e] = ex; s += ex;
    }
    float inv = 1.0f / s;
    bf16* ow = attn_w + (size_t)bh * 4096 + t * 64;
    for (int e = 0; e < 64; ++e) ow[e] = (bf16)(ssum[t][e] * inv);
  }
}

// ---------------------------------------------------------------------------
// PV: out^T[b][n][c] = (attn * v)^T, chunked over n. grid (8, 128).
// ---------------------------------------------------------------------------
__global__ __launch_bounds__(256) void attn_pv_kernel(
    const bf16* __restrict__ qkv, const bf16* __restrict__ attn_w,
    bf16* __restrict__ attn_t) {
  __shared__ __attribute__((aligned(16))) bf16 aw[64 * 72];
  __shared__ __attribute__((aligned(16))) bf16 Vs[128 * 72];  // reused as O^T staging
  int chunk = blockIdx.x, bh = blockIdx.y, b = bh >> 3, h = bh & 7;
  const bf16* vmat = qkv + ((size_t)b * QKV_M + 2 * INNER + h * 64) * NSPAT + chunk * 512;
  bf16* outt = attn_t + ((size_t)b * NSPAT + chunk * 512) * INNER + h * 64;

  int tid = threadIdx.x, lane = tid & 63, wid = tid >> 6;
  int lm = lane & 15, kqd = lane >> 4, d0 = wid * 16;

#pragma unroll
  for (int i = 0; i < 2; ++i) {
    int v = tid + i * 256;
    *(bf16x8*)&aw[(v >> 3) * 72 + (v & 7) * 8] = *(const bf16x8*)(attn_w + (size_t)bh * 4096 + v * 8);
  }
  __syncthreads();
  bf16x8 a0 = *(const bf16x8*)&aw[(d0 + lm) * 72 + kqd * 8];
  bf16x8 a1 = *(const bf16x8*)&aw[(d0 + lm) * 72 + 32 + kqd * 8];

  for (int nc = 0; nc < 512; nc += 128) {
    __syncthreads();
#pragma unroll
    for (int i = 0; i < 4; ++i) {
      int v = i * 256 + tid;
      int e = v & 63, nn = (v >> 6) * 8;
      bf16x8 d = *(const bf16x8*)(vmat + (size_t)e * NSPAT + nc + nn);
#pragma unroll
      for (int j = 0; j < 8; ++j) Vs[(nn + j) * 72 + e] = d[j];
    }
    __syncthreads();
    f32x4 o[8];
#pragma unroll
    for (int nt = 0; nt < 8; ++nt) {
      bf16x8 b0 = *(const bf16x8*)&Vs[(nt * 16 + lm) * 72 + kqd * 8];
      bf16x8 b1 = *(const bf16x8*)&Vs[(nt * 16 + lm) * 72 + 32 + kqd * 8];
      o[nt] = (f32x4){0.f, 0.f, 0.f, 0.f};
      o[nt] = __builtin_amdgcn_mfma_f32_16x16x32_bf16(a0, b0, o[nt], 0, 0, 0);
      o[nt] = __builtin_amdgcn_mfma_f32_16x16x32_bf16(a1, b1, o[nt], 0, 0, 0);
    }
    __syncthreads();
#pragma unroll
    for (int nt = 0; nt < 8; ++nt) {
      bf16x4 ov = { (bf16)o[nt][0], (bf16)o[nt][1], (bf16)o[nt][2], (bf16)o[nt][3] };
      *(bf16x4*)&Vs[(nt * 16 + lm) * 72 + d0 + kqd * 4] = ov;
    }
    __syncthreads();
#pragma unroll
    for (int i = 0; i < 4; ++i) {
      int v = i * 256 + tid;
      int n = v >> 3, dc = (v & 7) * 8;
      *(bf16x8*)(outt + (size_t)(nc + n) * INNER + dc) = *(const bf16x8*)&Vs[n * 72 + dc];
    }
  }
}

// ---------------------------------------------------------------------------
// LN stats + apply
// ---------------------------------------------------------------------------
__global__ void ln_stats_kernel(const float* __restrict__ part, float2* __restrict__ stats) {
  int b = threadIdx.x;
  if (b < 16) {
    const float invn = 1.0f / 2097152.0f;
    float mean = part[b * 2] * invn;
    float var  = part[b * 2 + 1] * invn - mean * mean;
    stats[b] = make_float2(mean, rsqrtf(var + 1e-5f));
  }
}

__global__ __launch_bounds__(256) void ln_apply_kernel(
    float* __restrict__ out, const float2* __restrict__ stats,
    const float* __restrict__ gamma, const float* __restrict__ beta) {
  size_t i4 = (size_t)blockIdx.x * 256 + threadIdx.x;
  size_t e  = i4 * 4;
  int b = (int)(e >> 21);
  int c = (int)((e >> 12) & 511);
  float2 st = stats[b];
  float g  = gamma[c] * st.y;
  float bb = beta[c] - st.x * g;
  float4* p = (float4*)out;
  float4 v = p[i4];
  v.x = v.x * g + bb; v.y = v.y * g + bb; v.z = v.z * g + bb; v.w = v.w * g + bb;
  p[i4] = v;
}

// ---------------------------------------------------------------------------
extern "C" void kernel_launch(void* const* d_in, const int* in_sizes, int n_in,
                              void* d_out, int out_size, void* d_ws, size_t ws_size,
                              hipStream_t stream) {
  const float* x      = (const float*)d_in[0];
  const float* w_qkv  = (const float*)d_in[1];
  const float* w_out  = (const float*)d_in[2];
  const float* b_out  = (const float*)d_in[3];
  const float* gamma  = (const float*)d_in[4];
  const float* beta   = (const float*)d_in[5];
  float* out = (float*)d_out;

  char* ws = (char*)d_ws;
  bf16*   xt      = (bf16*)(ws);                    // 64 MiB (B, N, C) — freed after QKV gemm
  float*  sc_part = (float*)(ws);                   // 16 MiB overlay (after xt's last use)
  bf16*   attn_w  = (bf16*)(ws + 16777216);         //  1 MiB overlay
  bf16*   wqkvb   = (bf16*)(ws + 67108864);         // 1.5 MiB
  bf16*   woutb   = (bf16*)(ws + 68681728);         // 0.5 MiB
  bf16*   qkvb    = (bf16*)(ws + 69206016);         // 192 MiB (B, 1536, N)
  bf16*   attn_t  = (bf16*)(ws + 270532608);        //  64 MiB (B, N, C)
  float*  part    = (float*)(ws + 337641472);       // 32 f32
  float2* stats   = (float2*)(ws + 337641600);      // 16 float2

  hipMemsetAsync(part, 0, 128, stream);

  transpose_cast_kernel<<<dim3(64, 8, BATCH), 256, 0, stream>>>(x, xt);
  cast_f32_bf16_kernel<<<768, 256, 0, stream>>>(w_qkv, wqkvb, 196608);
  cast_f32_bf16_kernel<<<256, 256, 0, stream>>>(w_out, woutb, 65536);

  // QKV projection: (1536x512) x (512x4096) per batch -> qkvb bf16
  gemm_tn_kernel<0><<<dim3(32, 12, BATCH), 256, 0, stream>>>(
      wqkvb, xt, (void*)qkvb, nullptr, nullptr, QKV_M, NSPAT, CDIM);

  // channel attention
  attn_scores_kernel<<<dim3(8, 128), 256, 0, stream>>>(qkvb, sc_part);
  attn_softmax_kernel<<<128, 256, 0, stream>>>(sc_part, attn_w);
  attn_pv_kernel<<<dim3(8, 128), 256, 0, stream>>>(qkvb, attn_w, attn_t);

  // output projection + bias + LN partials -> d_out f32
  gemm_tn_kernel<1><<<dim3(32, 4, BATCH), 256, 0, stream>>>(
      woutb, attn_t, (void*)out, b_out, part, INNER, NSPAT, CDIM);

  ln_stats_kernel<<<1, 16, 0, stream>>>(part, stats);
  ln_apply_kernel<<<32768, 256, 0, stream>>>(out, stats, gamma, beta);
}